// Round 4
// baseline (522.056 us; speedup 1.0000x reference)
//
#include <hip/hip_runtime.h>

// ---------------------------------------------------------------------------
// cosine_seqNet: out[b,o] = conv_b[o] + (1/6) * sum_{d,w} conv_w[o,d,w] *
//                 P[b,d,w],  P[b,d,w] = sum_{t=0..5} x[b,t+w,d]*cos[b,t+w]
// Shapes: B=256, S=10, D=4096, O=4096, W=5, K = D*W = 20480
// R7: R6 crashed on W OOB (SPLITS=2,NT=32 with grid 512 -> nt up to 255 ->
//     W rows up to 8191 > 4096). Fix: SPLITS=4, NT=32, grid 512 = 128
//     n-tiles x 4 splits. nt=bid>>2 (<=127), sp=bid&3 (one split per XCD,
//     A k-window 2.6MB L2-resident), 2 blocks/CU kept. Pipeline unchanged
//     from R6 (counted vmcnt, race-free: own-A retired via vmcnt(2) before
//     barrier; W(t+2) stays in flight across barriers via vmcnt(10)).
// ---------------------------------------------------------------------------

#define BDIM 256
#define SEQ 10
#define DDIM 4096
#define ODIM 4096
#define WDIM 5
#define GK 20480               // D*W
#define SPLITS 4
#define KSPLIT (GK / SPLITS)   // 5120
#define BK 64
#define KITERS (KSPLIT / BK)   // 80
#define NT 32                  // n-tile

typedef __bf16 bf16x8 __attribute__((ext_vector_type(8)));
typedef float f32x4 __attribute__((ext_vector_type(4)));

__device__ __forceinline__ unsigned short f2bf(float f) {
    union { float f; unsigned v; } c; c.f = f;
    unsigned r = c.v + 0x7FFFu + ((c.v >> 16) & 1u);   // RNE
    return (unsigned short)(r >> 16);
}
__device__ __forceinline__ void async16(void* lds, const void* g) {
    __builtin_amdgcn_global_load_lds(
        (const __attribute__((address_space(1))) void*)g,
        (__attribute__((address_space(3))) void*)lds, 16, 0, 0);
}

#define VMWAIT(n) asm volatile("s_waitcnt vmcnt(" #n ")" ::: "memory")
#define LGKM0()   asm volatile("s_waitcnt lgkmcnt(0)" ::: "memory")
#define SBAR()    __builtin_amdgcn_s_barrier()
#define SCHED0()  __builtin_amdgcn_sched_barrier(0)

// ---------------------------------------------------------------------------
// Kernel 1 (fused): cos[b,s] in shared, then P[b, d*5+w] = bf16(sum_t x*cos).
// ---------------------------------------------------------------------------
__global__ __launch_bounds__(256) void cosp_kernel(const float* __restrict__ x,
                                                   unsigned short* __restrict__ P)
{
    const int b = blockIdx.x;
    const int tid = threadIdx.x;
    const float* xb = x + (size_t)b * SEQ * DDIM;

    float dot[SEQ], sq[SEQ];
#pragma unroll
    for (int s = 0; s < SEQ; ++s) { dot[s] = 0.f; sq[s] = 0.f; }

    for (int base = 0; base < DDIM; base += 1024) {
        const int d = base + tid * 4;
        const f32x4 c4 = *(const f32x4*)(xb + 6 * DDIM + d);
#pragma unroll
        for (int s = 0; s < SEQ; ++s) {
            const f32x4 v4 = *(const f32x4*)(xb + s * DDIM + d);
            dot[s] += v4[0] * c4[0] + v4[1] * c4[1] + v4[2] * c4[2] + v4[3] * c4[3];
            sq[s]  += v4[0] * v4[0] + v4[1] * v4[1] + v4[2] * v4[2] + v4[3] * v4[3];
        }
    }
#pragma unroll
    for (int s = 0; s < SEQ; ++s) {
#pragma unroll
        for (int off = 32; off > 0; off >>= 1) {
            dot[s] += __shfl_down(dot[s], off, 64);
            sq[s]  += __shfl_down(sq[s], off, 64);
        }
    }
    __shared__ float red[4][2 * SEQ];
    __shared__ float cs[SEQ];
    const int wave = tid >> 6, lane = tid & 63;
    if (lane == 0) {
#pragma unroll
        for (int s = 0; s < SEQ; ++s) { red[wave][s] = dot[s]; red[wave][SEQ + s] = sq[s]; }
    }
    __syncthreads();
    if (tid == 0) {
        const float S6 = red[0][SEQ + 6] + red[1][SEQ + 6] + red[2][SEQ + 6] + red[3][SEQ + 6];
        const float cn = fmaxf(sqrtf(S6), 1e-8f);
#pragma unroll
        for (int s = 0; s < SEQ; ++s) {
            const float Dv = red[0][s] + red[1][s] + red[2][s] + red[3][s];
            const float Sv = red[0][SEQ + s] + red[1][SEQ + s] + red[2][SEQ + s] + red[3][SEQ + s];
            cs[s] = Dv / (fmaxf(sqrtf(Sv), 1e-8f) * cn);
        }
    }
    __syncthreads();

    float csr[SEQ];
#pragma unroll
    for (int s = 0; s < SEQ; ++s) csr[s] = cs[s];

    for (int chunk = 3; chunk >= 0; --chunk) {
        const int d0 = chunk * 1024 + tid * 4;
        const float* xd = xb + d0;
        float sc[SEQ][4];
#pragma unroll
        for (int s = 0; s < SEQ; ++s) {
            const f32x4 v4 = *(const f32x4*)(xd + s * DDIM);
            sc[s][0] = v4[0] * csr[s]; sc[s][1] = v4[1] * csr[s];
            sc[s][2] = v4[2] * csr[s]; sc[s][3] = v4[3] * csr[s];
        }
        __attribute__((aligned(16))) unsigned short o[20];
#pragma unroll
        for (int w = 0; w < WDIM; ++w) {
#pragma unroll
            for (int j = 0; j < 4; ++j) {
                const float p = sc[w][j] + sc[w + 1][j] + sc[w + 2][j] +
                                sc[w + 3][j] + sc[w + 4][j] + sc[w + 5][j];
                o[j * WDIM + w] = f2bf(p);
            }
        }
        unsigned short* dst = P + ((size_t)b * DDIM + d0) * WDIM;
#pragma unroll
        for (int q = 0; q < 5; ++q)
            *(uint2*)(dst + q * 4) = *(const uint2*)(o + q * 4);
    }
}

// ---------------------------------------------------------------------------
// Kernel 2: split-K GEMM.  Cpart[sp,m,n] = sum_k A[m,k]*W[n,k]
// Tile 256(m) x 32(n), BK=64, KITERS=80. A dbuf via global_load_lds
// (pre-swizzled source, linear dest); W 2-iter-ahead reg prefetch ->
// cvt bf16 -> swizzled ds_write. Per-iter vmem = 8 A-async + 2 W = 10.
// Schedule (race-free): stage A(t+1)+load W(t+2) early; COMPUTE(t);
// vmcnt(10) retires W(t+1) -> WRITE_W; vmcnt(2) retires own A(t+1);
// lgkmcnt(0); s_barrier.  W(t+2) stays in flight across the barrier.
// grid = 512: sp = bid&3 (one split per XCD), nt = bid>>2 (128 n-tiles).
// ---------------------------------------------------------------------------
__global__ __launch_bounds__(256, 2) void gemm_splitk_kernel(const unsigned short* __restrict__ A,
                                                             const float* __restrict__ W,
                                                             float* __restrict__ Cpart)
{
    const int bid = blockIdx.x;
    const int sp = bid & 3;       // split -> XCD affinity (A k-window L2-resident)
    const int nt = bid >> 2;      // 0..127
    const int tid = threadIdx.x;
    const int lane = tid & 63;
    const int wave = tid >> 6;

    __shared__ __align__(16) unsigned short lds_a[2][256 * BK];  // 2 x 32 KB
    __shared__ __align__(16) unsigned short lds_w[2][NT * BK];   // 2 x  4 KB

    f32x4 acc[4][2];
#pragma unroll
    for (int i = 0; i < 4; ++i)
#pragma unroll
        for (int j = 0; j < 2; ++j)
            acc[i][j] = (f32x4){0.f, 0.f, 0.f, 0.f};

    // A staging: 8 async16/thread; dest = q*4096 + tid*16 (linear);
    // source column oct pre-swizzled: oct = (tid&7) ^ (row&7).
    const int s_arow = tid >> 3;       // 0..31
    const int s_aoct = tid & 7;

    // W staging: row tid>>3 (0..31), 8 floats at col (tid&7)*8.
    const int s_wrow = tid >> 3;
    const float* wsrc = W + ((size_t)(nt * NT + s_wrow)) * GK + (tid & 7) * 8;
    const int wo0 = (((tid & 7)) ^ (s_wrow & 7)) * 8;   // phys oct elem offset

    // fragment read offsets (elements), [kh][*]; swizzled
    const int fm = lane & 15;
    const int fg = lane >> 4;
    int aoff[2][4], woff[2][2];
#pragma unroll
    for (int kh = 0; kh < 2; ++kh) {
#pragma unroll
        for (int i = 0; i < 4; ++i) {
            const int ra = wave * 64 + i * 16 + fm;
            aoff[kh][i] = ra * BK + (((kh * 4 + fg) ^ (ra & 7)) * 8);
        }
#pragma unroll
        for (int j = 0; j < 2; ++j) {
            const int rw = j * 16 + fm;
            woff[kh][j] = rw * BK + (((kh * 4 + fg) ^ (rw & 7)) * 8);
        }
    }

#define STAGE_A(buf, kk)                                                        \
    _Pragma("unroll")                                                           \
    for (int q = 0; q < 8; ++q) {                                               \
        const int row_ = q * 32 + s_arow;                                       \
        const unsigned short* src_ =                                            \
            A + (size_t)row_ * GK + (kk) + ((s_aoct ^ (row_ & 7)) * 8);         \
        async16((char*)&lds_a[buf][0] + q * 4096 + tid * 16, src_);             \
    }

#define LOAD_W(R0, R1, kk)                                                      \
    R0 = *(const f32x4*)(wsrc + (kk));                                          \
    R1 = *(const f32x4*)(wsrc + (kk) + 4);

#define WRITE_W(buf, R0, R1)                                                    \
    {                                                                           \
        bf16x8 v_;                                                              \
        _Pragma("unroll")                                                       \
        for (int e = 0; e < 4; ++e) { v_[e] = (__bf16)R0[e]; v_[4 + e] = (__bf16)R1[e]; } \
        *(bf16x8*)&lds_w[buf][s_wrow * BK + wo0] = v_;                          \
    }

#define COMPUTE(buf)                                                            \
    _Pragma("unroll")                                                           \
    for (int kh = 0; kh < 2; ++kh) {                                            \
        bf16x8 af[4], wf[2];                                                    \
        _Pragma("unroll")                                                       \
        for (int i = 0; i < 4; ++i) af[i] = *(const bf16x8*)&lds_a[buf][aoff[kh][i]]; \
        _Pragma("unroll")                                                       \
        for (int j = 0; j < 2; ++j) wf[j] = *(const bf16x8*)&lds_w[buf][woff[kh][j]]; \
        _Pragma("unroll")                                                       \
        for (int i = 0; i < 4; ++i)                                             \
            _Pragma("unroll")                                                   \
            for (int j = 0; j < 2; ++j)                                         \
                acc[i][j] = __builtin_amdgcn_mfma_f32_16x16x32_bf16(            \
                    af[i], wf[j], acc[i][j], 0, 0, 0);                          \
    }

    const int ksp = sp * KSPLIT;
    f32x4 wA0, wA1;   // reg set A (even-iter W loads)
    f32x4 wB0, wB1;   // reg set B (odd-iter W loads)

    // ---- prologue -----------------------------------------------------------
    LOAD_W(wA0, wA1, ksp);                 // W(0), 2 vmem
    STAGE_A(0, ksp);                       // A(0), 8 vmem
    LOAD_W(wB0, wB1, ksp + BK);            // W(1), 2 vmem -> outstanding 12
    VMWAIT(10); SCHED0();                  // W(0) landed
    WRITE_W(0, wA0, wA1);
    VMWAIT(2); SCHED0();                   // A(0) landed (W(1) still flying)
    LGKM0();
    SBAR(); SCHED0();

    int kbase = ksp;
    // ---- steady state: t = 0..77, unrolled x2 (static bufs/reg sets) -------
    for (int tt = 0; tt < (KITERS - 2) / 2; ++tt) {
        // t even: cur buf0; stage A(t+1)->buf1; load W(t+2)->setA; write W(t+1) from setB
        SCHED0();
        STAGE_A(1, kbase + BK);
        LOAD_W(wA0, wA1, kbase + 2 * BK);
        COMPUTE(0);
        VMWAIT(10); SCHED0();              // W(t+1) landed (newest 10 = A(t+1)+W(t+2))
        WRITE_W(1, wB0, wB1);
        VMWAIT(2); SCHED0();               // own A(t+1) landed; W(t+2) stays in flight
        LGKM0();
        SBAR(); SCHED0();
        kbase += BK;
        // t odd: mirror
        STAGE_A(0, kbase + BK);
        LOAD_W(wB0, wB1, kbase + 2 * BK);
        COMPUTE(1);
        VMWAIT(10); SCHED0();
        WRITE_W(0, wA0, wA1);
        VMWAIT(2); SCHED0();
        LGKM0();
        SBAR(); SCHED0();
        kbase += BK;
    }
    // ---- tail t = 78 (even): stage A(79); W(79) already loaded into setB ---
    STAGE_A(1, kbase + BK);
    COMPUTE(0);
    VMWAIT(8); SCHED0();                   // W(79) landed (newest 8 = A(79))
    WRITE_W(1, wB0, wB1);
    VMWAIT(0); SCHED0();                   // A(79) landed
    LGKM0();
    SBAR(); SCHED0();
    // ---- tail t = 79 (odd) --------------------------------------------------
    COMPUTE(1);

    // C/D layout: col(n) = lane&15, row(m) = (lane>>4)*4 + reg  [m89-verified]
    float* Cp = Cpart + (size_t)sp * (BDIM * ODIM);
    const int mbase = wave * 64 + fg * 4;
    const int nbase = nt * NT + fm;
#pragma unroll
    for (int i = 0; i < 4; ++i)
#pragma unroll
        for (int j = 0; j < 2; ++j) {
            const int n = nbase + j * 16;
#pragma unroll
            for (int r = 0; r < 4; ++r) {
                const int m = mbase + i * 16 + r;
                Cp[(size_t)m * ODIM + n] = acc[i][j][r];
            }
        }
#undef STAGE_A
#undef LOAD_W
#undef WRITE_W
#undef COMPUTE
}

// ---------------------------------------------------------------------------
// Kernel 3: out[b,o] = sum_sp partial[sp,b,o] / 6 + conv_b[o]
// ---------------------------------------------------------------------------
__global__ __launch_bounds__(256) void reduce_kernel(const float* __restrict__ part,
                                                     const float* __restrict__ bias,
                                                     float* __restrict__ out)
{
    const int idx = (blockIdx.x * 256 + threadIdx.x) * 4;
    f32x4 s = (f32x4){0.f, 0.f, 0.f, 0.f};
#pragma unroll
    for (int sp = 0; sp < SPLITS; ++sp) {
        const f32x4 v = *(const f32x4*)(part + (size_t)sp * (BDIM * ODIM) + idx);
        s[0] += v[0]; s[1] += v[1]; s[2] += v[2]; s[3] += v[3];
    }
    const int n = idx & (ODIM - 1);
    const f32x4 b4 = *(const f32x4*)(bias + n);
    const float inv6 = 1.0f / 6.0f;
    f32x4 o;
#pragma unroll
    for (int e = 0; e < 4; ++e) o[e] = s[e] * inv6 + b4[e];
    *(f32x4*)(out + idx) = o;
}

// ---------------------------------------------------------------------------
extern "C" void kernel_launch(void* const* d_in, const int* in_sizes, int n_in,
                              void* d_out, int out_size, void* d_ws, size_t ws_size,
                              hipStream_t stream) {
    const float* x  = (const float*)d_in[0];   // fp32 (256,10,4096)
    const float* cw = (const float*)d_in[1];   // fp32 (4096,4096,5)
    const float* cb = (const float*)d_in[2];   // fp32 (4096,)
    float* out = (float*)d_out;                // fp32 (256,4096)

    char* ws = (char*)d_ws;
    unsigned short* P = (unsigned short*)(ws + 16384);               // 10.49 MB bf16
    float* parts = (float*)(ws + 16384 + (size_t)BDIM * GK * 2);     // 16.78 MB fp32

    hipLaunchKernelGGL(cosp_kernel,        dim3(256),  dim3(256), 0, stream, x, P);
    hipLaunchKernelGGL(gemm_splitk_kernel, dim3(512),  dim3(256), 0, stream, P, cw, parts);
    hipLaunchKernelGGL(reduce_kernel,      dim3(1024), dim3(256), 0, stream, parts, cb, out);
}

// Round 5
// 492.736 us; speedup vs baseline: 1.0595x; 1.0595x over previous
//
#include <hip/hip_runtime.h>

// ---------------------------------------------------------------------------
// cosine_seqNet: out[b,o] = conv_b[o] + (1/6) * sum_{d,w} conv_w[o,d,w] *
//                 P[b,d,w],  P[b,d,w] = sum_{t=0..5} x[b,t+w,d]*cos[b,t+w]
// Shapes: B=256, S=10, D=4096, O=4096, W=5, K = D*W = 20480
// R8: R7 (SPLITS=4/NT=32, KITERS=80) regressed: doubled iteration count +
//     halved in-flight W -> latency-paced loop. Revert to R5 geometry
//     (SPLITS=8, NT=64, KITERS=40, 12 vmem/iter). Deltas vs R5:
//     (1) race-free reorder: COMPUTE(t) issued BEFORE the counted waits
//         (inputs barrier-guaranteed: each wave retires its OWN A via
//         vmcnt(4) before s_barrier), so MFMA overlaps in-flight loads;
//     (2) bf16 partials: parts round-trip 67 -> 33.5 MB.
// ---------------------------------------------------------------------------

#define BDIM 256
#define SEQ 10
#define DDIM 4096
#define ODIM 4096
#define WDIM 5
#define GK 20480               // D*W
#define SPLITS 8
#define KSPLIT (GK / SPLITS)   // 2560
#define BK 64
#define KITERS (KSPLIT / BK)   // 40
#define NT 64                  // n-tile

typedef __bf16 bf16x8 __attribute__((ext_vector_type(8)));
typedef float f32x4 __attribute__((ext_vector_type(4)));
typedef unsigned short u16x8 __attribute__((ext_vector_type(8)));

__device__ __forceinline__ unsigned short f2bf(float f) {
    union { float f; unsigned v; } c; c.f = f;
    unsigned r = c.v + 0x7FFFu + ((c.v >> 16) & 1u);   // RNE
    return (unsigned short)(r >> 16);
}
__device__ __forceinline__ float bf2f(unsigned short u) {
    union { unsigned v; float f; } c; c.v = ((unsigned)u) << 16;
    return c.f;
}
__device__ __forceinline__ void async16(void* lds, const void* g) {
    __builtin_amdgcn_global_load_lds(
        (const __attribute__((address_space(1))) void*)g,
        (__attribute__((address_space(3))) void*)lds, 16, 0, 0);
}

#define VMWAIT(n) asm volatile("s_waitcnt vmcnt(" #n ")" ::: "memory")
#define LGKM0()   asm volatile("s_waitcnt lgkmcnt(0)" ::: "memory")
#define SBAR()    __builtin_amdgcn_s_barrier()
#define SCHED0()  __builtin_amdgcn_sched_barrier(0)

// ---------------------------------------------------------------------------
// Kernel 1 (fused): cos[b,s] in shared, then P[b, d*5+w] = bf16(sum_t x*cos).
// ---------------------------------------------------------------------------
__global__ __launch_bounds__(256) void cosp_kernel(const float* __restrict__ x,
                                                   unsigned short* __restrict__ P)
{
    const int b = blockIdx.x;
    const int tid = threadIdx.x;
    const float* xb = x + (size_t)b * SEQ * DDIM;

    float dot[SEQ], sq[SEQ];
#pragma unroll
    for (int s = 0; s < SEQ; ++s) { dot[s] = 0.f; sq[s] = 0.f; }

    for (int base = 0; base < DDIM; base += 1024) {
        const int d = base + tid * 4;
        const f32x4 c4 = *(const f32x4*)(xb + 6 * DDIM + d);
#pragma unroll
        for (int s = 0; s < SEQ; ++s) {
            const f32x4 v4 = *(const f32x4*)(xb + s * DDIM + d);
            dot[s] += v4[0] * c4[0] + v4[1] * c4[1] + v4[2] * c4[2] + v4[3] * c4[3];
            sq[s]  += v4[0] * v4[0] + v4[1] * v4[1] + v4[2] * v4[2] + v4[3] * v4[3];
        }
    }
#pragma unroll
    for (int s = 0; s < SEQ; ++s) {
#pragma unroll
        for (int off = 32; off > 0; off >>= 1) {
            dot[s] += __shfl_down(dot[s], off, 64);
            sq[s]  += __shfl_down(sq[s], off, 64);
        }
    }
    __shared__ float red[4][2 * SEQ];
    __shared__ float cs[SEQ];
    const int wave = tid >> 6, lane = tid & 63;
    if (lane == 0) {
#pragma unroll
        for (int s = 0; s < SEQ; ++s) { red[wave][s] = dot[s]; red[wave][SEQ + s] = sq[s]; }
    }
    __syncthreads();
    if (tid == 0) {
        const float S6 = red[0][SEQ + 6] + red[1][SEQ + 6] + red[2][SEQ + 6] + red[3][SEQ + 6];
        const float cn = fmaxf(sqrtf(S6), 1e-8f);
#pragma unroll
        for (int s = 0; s < SEQ; ++s) {
            const float Dv = red[0][s] + red[1][s] + red[2][s] + red[3][s];
            const float Sv = red[0][SEQ + s] + red[1][SEQ + s] + red[2][SEQ + s] + red[3][SEQ + s];
            cs[s] = Dv / (fmaxf(sqrtf(Sv), 1e-8f) * cn);
        }
    }
    __syncthreads();

    float csr[SEQ];
#pragma unroll
    for (int s = 0; s < SEQ; ++s) csr[s] = cs[s];

    for (int chunk = 3; chunk >= 0; --chunk) {
        const int d0 = chunk * 1024 + tid * 4;
        const float* xd = xb + d0;
        float sc[SEQ][4];
#pragma unroll
        for (int s = 0; s < SEQ; ++s) {
            const f32x4 v4 = *(const f32x4*)(xd + s * DDIM);
            sc[s][0] = v4[0] * csr[s]; sc[s][1] = v4[1] * csr[s];
            sc[s][2] = v4[2] * csr[s]; sc[s][3] = v4[3] * csr[s];
        }
        __attribute__((aligned(16))) unsigned short o[20];
#pragma unroll
        for (int w = 0; w < WDIM; ++w) {
#pragma unroll
            for (int j = 0; j < 4; ++j) {
                const float p = sc[w][j] + sc[w + 1][j] + sc[w + 2][j] +
                                sc[w + 3][j] + sc[w + 4][j] + sc[w + 5][j];
                o[j * WDIM + w] = f2bf(p);
            }
        }
        unsigned short* dst = P + ((size_t)b * DDIM + d0) * WDIM;
#pragma unroll
        for (int q = 0; q < 5; ++q)
            *(uint2*)(dst + q * 4) = *(const uint2*)(o + q * 4);
    }
}

// ---------------------------------------------------------------------------
// Kernel 2: split-K GEMM.  Cpart[sp,m,n] = sum_k A[m,k]*W[n,k]  (bf16 out)
// Tile 256(m) x 64(n), BK=64, KITERS=40. A dbuf via global_load_lds
// (pre-swizzled source, linear dest); W 2-iter-ahead reg prefetch ->
// cvt bf16 -> swizzled ds_write. Per-iter vmem = 8 A-async + 4 W = 12.
// Iteration t: STAGE_A(t+1); LOAD_W(t+2); COMPUTE(t)   [inputs guaranteed:
//   own A(t) retired via vmcnt(4) before previous s_barrier, W(t) ds_written
//   before it]; vmcnt(12) retires W(t+1) -> WRITE_W; vmcnt(4) retires own
//   A(t+1); lgkmcnt(0); s_barrier.  W(t+2) stays in flight across barrier.
// grid = 512: sp = bid&7 (one split per XCD, A slice 1.31MB L2-resident),
// nt = bid>>3 (64 n-tiles), 2 blocks/CU.
// ---------------------------------------------------------------------------
__global__ __launch_bounds__(256, 2) void gemm_splitk_kernel(const unsigned short* __restrict__ A,
                                                             const float* __restrict__ W,
                                                             unsigned short* __restrict__ Cpart)
{
    const int bid = blockIdx.x;
    const int sp = bid & 7;       // split -> XCD affinity
    const int nt = bid >> 3;      // 0..63
    const int tid = threadIdx.x;
    const int lane = tid & 63;
    const int wave = tid >> 6;

    __shared__ __align__(16) unsigned short lds_a[2][256 * BK];  // 2 x 32 KB
    __shared__ __align__(16) unsigned short lds_w[2][NT * BK];   // 2 x  8 KB

    f32x4 acc[4][4];
#pragma unroll
    for (int i = 0; i < 4; ++i)
#pragma unroll
        for (int j = 0; j < 4; ++j)
            acc[i][j] = (f32x4){0.f, 0.f, 0.f, 0.f};

    // A staging: 8 async16/thread; dest = q*4096 + tid*16 (linear);
    // source column oct pre-swizzled: oct = (tid&7) ^ (row&7).
    const int s_arow = tid >> 3;       // 0..31
    const int s_aoct = tid & 7;

    // W staging: row tid>>2 (0..63), 16 floats at col (tid&3)*16.
    const int s_wrow = tid >> 2;
    const float* wsrc = W + ((size_t)(nt * NT + s_wrow)) * GK + (tid & 3) * 16;
    const int wo0 = (((tid & 3) * 2)     ^ (s_wrow & 7)) * 8;
    const int wo1 = (((tid & 3) * 2 + 1) ^ (s_wrow & 7)) * 8;

    // fragment read offsets (elements), [kh][*]; swizzled
    const int fm = lane & 15;
    const int fg = lane >> 4;
    int aoff[2][4], woff[2][4];
#pragma unroll
    for (int kh = 0; kh < 2; ++kh) {
#pragma unroll
        for (int i = 0; i < 4; ++i) {
            const int ra = wave * 64 + i * 16 + fm;
            aoff[kh][i] = ra * BK + (((kh * 4 + fg) ^ (ra & 7)) * 8);
        }
#pragma unroll
        for (int j = 0; j < 4; ++j) {
            const int rw = j * 16 + fm;
            woff[kh][j] = rw * BK + (((kh * 4 + fg) ^ (rw & 7)) * 8);
        }
    }

#define STAGE_A(buf, kk)                                                        \
    _Pragma("unroll")                                                           \
    for (int q = 0; q < 8; ++q) {                                               \
        const int row_ = q * 32 + s_arow;                                       \
        const unsigned short* src_ =                                            \
            A + (size_t)row_ * GK + (kk) + ((s_aoct ^ (row_ & 7)) * 8);         \
        async16((char*)&lds_a[buf][0] + q * 4096 + tid * 16, src_);             \
    }

#define LOAD_W(R0, R1, R2, R3, kk)                                              \
    R0 = *(const f32x4*)(wsrc + (kk));                                          \
    R1 = *(const f32x4*)(wsrc + (kk) + 4);                                      \
    R2 = *(const f32x4*)(wsrc + (kk) + 8);                                      \
    R3 = *(const f32x4*)(wsrc + (kk) + 12);

#define WRITE_W(buf, R0, R1, R2, R3)                                            \
    {                                                                           \
        bf16x8 lo_, hi_;                                                        \
        _Pragma("unroll")                                                       \
        for (int e = 0; e < 4; ++e) {                                           \
            lo_[e] = (__bf16)R0[e]; lo_[4 + e] = (__bf16)R1[e];                 \
            hi_[e] = (__bf16)R2[e]; hi_[4 + e] = (__bf16)R3[e];                 \
        }                                                                       \
        *(bf16x8*)&lds_w[buf][s_wrow * BK + wo0] = lo_;                         \
        *(bf16x8*)&lds_w[buf][s_wrow * BK + wo1] = hi_;                         \
    }

#define COMPUTE(buf)                                                            \
    _Pragma("unroll")                                                           \
    for (int kh = 0; kh < 2; ++kh) {                                            \
        bf16x8 af[4], wf[4];                                                    \
        _Pragma("unroll")                                                       \
        for (int i = 0; i < 4; ++i) af[i] = *(const bf16x8*)&lds_a[buf][aoff[kh][i]]; \
        _Pragma("unroll")                                                       \
        for (int j = 0; j < 4; ++j) wf[j] = *(const bf16x8*)&lds_w[buf][woff[kh][j]]; \
        _Pragma("unroll")                                                       \
        for (int i = 0; i < 4; ++i)                                             \
            _Pragma("unroll")                                                   \
            for (int j = 0; j < 4; ++j)                                         \
                acc[i][j] = __builtin_amdgcn_mfma_f32_16x16x32_bf16(            \
                    af[i], wf[j], acc[i][j], 0, 0, 0);                          \
    }

    const int ksp = sp * KSPLIT;
    f32x4 wA0, wA1, wA2, wA3;   // reg set A (even-iter W loads)
    f32x4 wB0, wB1, wB2, wB3;   // reg set B (odd-iter W loads)

    // ---- prologue -----------------------------------------------------------
    LOAD_W(wA0, wA1, wA2, wA3, ksp);           // W(0), 4 vmem
    STAGE_A(0, ksp);                           // A(0), 8 vmem
    LOAD_W(wB0, wB1, wB2, wB3, ksp + BK);      // W(1), 4 vmem -> 16 outstanding
    VMWAIT(8); SCHED0();                       // W(0) landed
    WRITE_W(0, wA0, wA1, wA2, wA3);
    VMWAIT(4); SCHED0();                       // A(0) landed (W(1) still flying)
    LGKM0();
    SBAR(); SCHED0();

    int kbase = ksp;
    // ---- steady state: t = 0..37, unrolled x2 (static bufs/reg sets) -------
    for (int tt = 0; tt < (KITERS - 2) / 2; ++tt) {
        // t even: cur buf0; stage A(t+1)->buf1; load W(t+2)->setA;
        //         COMPUTE(t); then write W(t+1) from setB
        SCHED0();
        STAGE_A(1, kbase + BK);
        LOAD_W(wA0, wA1, wA2, wA3, kbase + 2 * BK);
        COMPUTE(0);
        VMWAIT(12); SCHED0();              // W(t+1) landed (newest 12 = A(t+1)+W(t+2))
        WRITE_W(1, wB0, wB1, wB2, wB3);
        VMWAIT(4); SCHED0();               // own A(t+1) landed; W(t+2) stays in flight
        LGKM0();
        SBAR(); SCHED0();
        kbase += BK;
        // t odd: mirror
        STAGE_A(0, kbase + BK);
        LOAD_W(wB0, wB1, wB2, wB3, kbase + 2 * BK);
        COMPUTE(1);
        VMWAIT(12); SCHED0();
        WRITE_W(0, wA0, wA1, wA2, wA3);
        VMWAIT(4); SCHED0();
        LGKM0();
        SBAR(); SCHED0();
        kbase += BK;
    }
    // ---- tail t = 38 (even): stage A(39); W(39) already loaded into setB ---
    STAGE_A(1, kbase + BK);
    COMPUTE(0);
    VMWAIT(8); SCHED0();                   // W(39) landed (newest 8 = A(39))
    WRITE_W(1, wB0, wB1, wB2, wB3);
    VMWAIT(0); SCHED0();                   // A(39) landed
    LGKM0();
    SBAR(); SCHED0();
    // ---- tail t = 39 (odd) --------------------------------------------------
    COMPUTE(1);

    // C/D layout: col(n) = lane&15, row(m) = (lane>>4)*4 + reg  [m89-verified]
    unsigned short* Cp = Cpart + (size_t)sp * (BDIM * ODIM);
    const int mbase = wave * 64 + fg * 4;
    const int nbase = nt * NT + fm;
#pragma unroll
    for (int i = 0; i < 4; ++i)
#pragma unroll
        for (int j = 0; j < 4; ++j) {
            const int n = nbase + j * 16;
#pragma unroll
            for (int r = 0; r < 4; ++r) {
                const int m = mbase + i * 16 + r;
                Cp[(size_t)m * ODIM + n] = f2bf(acc[i][j][r]);
            }
        }
#undef STAGE_A
#undef LOAD_W
#undef WRITE_W
#undef COMPUTE
}

// ---------------------------------------------------------------------------
// Kernel 3: out[b,o] = sum_sp bf16 partial[sp,b,o] / 6 + conv_b[o]
// 8 outputs/thread, grid 512.
// ---------------------------------------------------------------------------
__global__ __launch_bounds__(256) void reduce_kernel(const unsigned short* __restrict__ part,
                                                     const float* __restrict__ bias,
                                                     float* __restrict__ out)
{
    const int idx = (blockIdx.x * 256 + threadIdx.x) * 8;
    float s[8];
#pragma unroll
    for (int e = 0; e < 8; ++e) s[e] = 0.f;
#pragma unroll
    for (int sp = 0; sp < SPLITS; ++sp) {
        const u16x8 v = *(const u16x8*)(part + (size_t)sp * (BDIM * ODIM) + idx);
#pragma unroll
        for (int e = 0; e < 8; ++e) s[e] += bf2f(v[e]);
    }
    const int n = idx & (ODIM - 1);
    const float inv6 = 1.0f / 6.0f;
    f32x4 o0, o1;
#pragma unroll
    for (int e = 0; e < 4; ++e) {
        o0[e] = s[e] * inv6 + bias[n + e];
        o1[e] = s[4 + e] * inv6 + bias[n + 4 + e];
    }
    *(f32x4*)(out + idx) = o0;
    *(f32x4*)(out + idx + 4) = o1;
}

// ---------------------------------------------------------------------------
extern "C" void kernel_launch(void* const* d_in, const int* in_sizes, int n_in,
                              void* d_out, int out_size, void* d_ws, size_t ws_size,
                              hipStream_t stream) {
    const float* x  = (const float*)d_in[0];   // fp32 (256,10,4096)
    const float* cw = (const float*)d_in[1];   // fp32 (4096,4096,5)
    const float* cb = (const float*)d_in[2];   // fp32 (4096,)
    float* out = (float*)d_out;                // fp32 (256,4096)

    char* ws = (char*)d_ws;
    unsigned short* P = (unsigned short*)(ws + 16384);               // 10.49 MB bf16
    unsigned short* parts = (unsigned short*)(ws + 16384 + (size_t)BDIM * GK * 2); // 16.78 MB bf16

    hipLaunchKernelGGL(cosp_kernel,        dim3(256),  dim3(256), 0, stream, x, P);
    hipLaunchKernelGGL(gemm_splitk_kernel, dim3(512),  dim3(256), 0, stream, P, cw, parts);
    hipLaunchKernelGGL(reduce_kernel,      dim3(512),  dim3(256), 0, stream, parts, cb, out);
}